// Round 1
// baseline (140.747 us; speedup 1.0000x reference)
//
#include <hip/hip_runtime.h>

#define NC 20
#define CH 30

constexpr int BLOCK = 128;
constexpr int CELLS_PER_TILE = 128;
constexpr int TILE_FLOATS = CELLS_PER_TILE * CH;   // 3840 floats = 15360 B per array
constexpr int TILE_V4 = TILE_FLOATS / 4;           // 960 float4 chunks per array
constexpr int NBLOCKS = 1280;                      // 5 blocks/CU * 256 CU

// Per-cell YOLOv1 loss. t = y_true cell (30 floats, 8B-aligned), p = y_pred cell.
__device__ __forceinline__ float cell_loss(const float* __restrict__ tf,
                                           const float* __restrict__ pf) {
    const float2* t2 = (const float2*)tf;
    const float2* p2 = (const float2*)pf;

    // class loss: sum over 20 channels of (t-p)^2
    float cl = 0.f;
#pragma unroll
    for (int c = 0; c < NC / 2; ++c) {
        float2 a = t2[c], b = p2[c];
        float d0 = a.x - b.x, d1 = a.y - b.y;
        cl = fmaf(d0, d0, cl);
        cl = fmaf(d1, d1, cl);
    }
    float2 v10 = t2[10], v11 = t2[11];
    float th = tf[24];
    float obj = v10.x, tx = v10.y, ty = v11.x, tw = v11.y;
    float2 q10 = p2[10], q11 = p2[11], q12 = p2[12], q13 = p2[13], q14 = p2[14];
    float conf0 = q10.x, px0 = q10.y, py0 = q11.x, pw0 = q11.y, ph0 = q12.x;
    float conf1 = q12.y, px1 = q13.x, py1 = q13.y, pw1 = q14.x, ph1 = q14.y;

    // true-box corners (replicate reference arithmetic exactly: corners then diffs)
    float t_x1 = tx - tw * 0.5f, t_x2 = tx + tw * 0.5f;
    float t_y1 = ty - th * 0.5f, t_y2 = ty + th * 0.5f;
    float ta = fabsf((t_x2 - t_x1) * (t_y2 - t_y1));

    // IoU box 0
    float b_x1 = px0 - pw0 * 0.5f, b_x2 = px0 + pw0 * 0.5f;
    float b_y1 = py0 - ph0 * 0.5f, b_y2 = py0 + ph0 * 0.5f;
    float ix = fmaxf(fminf(t_x2, b_x2) - fmaxf(t_x1, b_x1), 0.f);
    float iy = fmaxf(fminf(t_y2, b_y2) - fmaxf(t_y1, b_y1), 0.f);
    float inter0 = ix * iy;
    float a0 = fabsf((b_x2 - b_x1) * (b_y2 - b_y1));
    float iou0 = inter0 * __builtin_amdgcn_rcpf(ta + a0 - inter0 + 1e-6f);

    // IoU box 1
    float c_x1 = px1 - pw1 * 0.5f, c_x2 = px1 + pw1 * 0.5f;
    float c_y1 = py1 - ph1 * 0.5f, c_y2 = py1 + ph1 * 0.5f;
    float jx = fmaxf(fminf(t_x2, c_x2) - fmaxf(t_x1, c_x1), 0.f);
    float jy = fmaxf(fminf(t_y2, c_y2) - fmaxf(t_y1, c_y1), 0.f);
    float inter1 = jx * jy;
    float a1 = fabsf((c_x2 - c_x1) * (c_y2 - c_y1));
    float iou1 = inter1 * __builtin_amdgcn_rcpf(ta + a1 - inter1 + 1e-6f);

    // argmax over [iou0, iou1], first-max-on-tie => box0 when equal
    bool sel1 = iou1 > iou0;
    float conf = sel1 ? conf1 : conf0;
    float piou = sel1 ? iou1 : iou0;
    float px = sel1 ? px1 : px0;
    float py = sel1 ? py1 : py0;
    float pw = sel1 ? pw1 : pw0;
    float ph = sel1 ? ph1 : ph0;

    float dx = tx - px, dy = ty - py;
    float xy = dx * dx + dy * dy;
    float sgw = (pw > 0.f) ? 1.f : ((pw < 0.f) ? -1.f : 0.f);
    float sgh = (ph > 0.f) ? 1.f : ((ph < 0.f) ? -1.f : 0.f);
    float dw = __builtin_amdgcn_sqrtf(tw) - sgw * __builtin_amdgcn_sqrtf(fabsf(pw) + 1e-6f);
    float dh = __builtin_amdgcn_sqrtf(th) - sgh * __builtin_amdgcn_sqrtf(fabsf(ph) + 1e-6f);
    float wh = dw * dw + dh * dh;
    float dob = piou - conf;

    // 5*box + obj + 0.5*noobj + class
    return obj * (5.f * (xy + wh) + dob * dob + cl) + (1.f - obj) * (0.5f * conf * conf);
}

__global__ __launch_bounds__(BLOCK) void yolo_loss_kernel(
    const float* __restrict__ yt, const float* __restrict__ yp,
    float* __restrict__ out, int ncells) {
    __shared__ float st[TILE_FLOATS];
    __shared__ float sp[TILE_FLOATS];
    __shared__ float wsum[BLOCK / 64];

    const int tid = threadIdx.x;
    const int lane = tid & 63;
    const int wvb = tid & ~63;  // wave's base thread index within block

    const int full_tiles = ncells / CELLS_PER_TILE;
    const int ntiles = (ncells + CELLS_PER_TILE - 1) / CELLS_PER_TILE;

    float acc = 0.f;

    for (int tile = blockIdx.x; tile < ntiles; tile += gridDim.x) {
        if (tile < full_tiles) {
            const size_t fbase = (size_t)tile * TILE_FLOATS;
            const float4* gt4 = (const float4*)(yt + fbase);
            const float4* gp4 = (const float4*)(yp + fbase);
            // async global->LDS staging, 16B per lane, wave-uniform LDS base
#pragma unroll
            for (int i = 0; i < (TILE_V4 + BLOCK - 1) / BLOCK; ++i) {
                int kw = i * BLOCK + wvb;       // wave-uniform chunk base (float4 idx)
                if (kw < TILE_V4) {             // wave-uniform predicate
                    __builtin_amdgcn_global_load_lds(
                        (const __attribute__((address_space(1))) void*)(gt4 + kw + lane),
                        (__attribute__((address_space(3))) void*)(st + (size_t)kw * 4),
                        16, 0, 0);
                    __builtin_amdgcn_global_load_lds(
                        (const __attribute__((address_space(1))) void*)(gp4 + kw + lane),
                        (__attribute__((address_space(3))) void*)(sp + (size_t)kw * 4),
                        16, 0, 0);
                }
            }
            __syncthreads();  // drains vmcnt (global_load_lds) before LDS reads
            acc += cell_loss(st + tid * CH, sp + tid * CH);
            __syncthreads();  // protect LDS before next tile overwrites
        } else {
            // tail tile (doesn't trigger for BATCH=65536: 3,211,264 % 128 == 0)
            int cell = tile * CELLS_PER_TILE + tid;
            if (cell < ncells) {
                float tt[CH], pp[CH];
                const float2* g2 = (const float2*)(yt + (size_t)cell * CH);
                const float2* h2 = (const float2*)(yp + (size_t)cell * CH);
#pragma unroll
                for (int j = 0; j < CH / 2; ++j) {
                    float2 v = g2[j]; tt[2 * j] = v.x; tt[2 * j + 1] = v.y;
                    float2 w = h2[j]; pp[2 * j] = w.x; pp[2 * j + 1] = w.y;
                }
                acc += cell_loss(tt, pp);
            }
        }
    }

    // wave reduction (64-wide), then cross-wave via LDS, one atomic per block
#pragma unroll
    for (int off = 32; off > 0; off >>= 1)
        acc += __shfl_down(acc, off, 64);
    if (lane == 0) wsum[tid >> 6] = acc;
    __syncthreads();
    if (tid == 0) {
        float s = 0.f;
#pragma unroll
        for (int w = 0; w < BLOCK / 64; ++w) s += wsum[w];
        atomicAdd(out, s);
    }
}

extern "C" void kernel_launch(void* const* d_in, const int* in_sizes, int n_in,
                              void* d_out, int out_size, void* d_ws, size_t ws_size,
                              hipStream_t stream) {
    const float* yt = (const float*)d_in[0];
    const float* yp = (const float*)d_in[1];
    float* out = (float*)d_out;

    const int ncells = in_sizes[0] / CH;
    const int ntiles = (ncells + CELLS_PER_TILE - 1) / CELLS_PER_TILE;

    // d_out is poisoned once and never re-poisoned between replays; we accumulate
    // atomically, so zero it on every launch (async memset is graph-capturable).
    hipMemsetAsync(d_out, 0, (size_t)out_size * sizeof(float), stream);

    int nblocks = NBLOCKS < ntiles ? NBLOCKS : ntiles;
    yolo_loss_kernel<<<nblocks, BLOCK, 0, stream>>>(yt, yp, out, ncells);
}

// Round 2
// 135.375 us; speedup vs baseline: 1.0397x; 1.0397x over previous
//
#include <hip/hip_runtime.h>

#define NC 20
#define CH 30

constexpr int WAVE = 64;
constexpr int CELLS_PER_TILE = 64;                 // one cell per lane per tile
constexpr int TILE_V4 = CELLS_PER_TILE * CH / 4;   // 480 float4 chunks per array
constexpr int LDS_FLOATS = 512 * 4;                // padded to 8 full wave-loads (2048 floats)
constexpr int NBLOCKS = 1024;                      // 50,176 tiles / 1024 = 49 exactly; 4 blocks/CU

// Per-cell YOLOv1 loss (validated round 1, absmax 0.0). 8B-aligned inputs.
__device__ __forceinline__ float cell_loss(const float* __restrict__ tf,
                                           const float* __restrict__ pf) {
    const float2* t2 = (const float2*)tf;
    const float2* p2 = (const float2*)pf;

    float cl = 0.f;
#pragma unroll
    for (int c = 0; c < NC / 2; ++c) {
        float2 a = t2[c], b = p2[c];
        float d0 = a.x - b.x, d1 = a.y - b.y;
        cl = fmaf(d0, d0, cl);
        cl = fmaf(d1, d1, cl);
    }
    float2 v10 = t2[10], v11 = t2[11];
    float th = tf[24];
    float obj = v10.x, tx = v10.y, ty = v11.x, tw = v11.y;
    float2 q10 = p2[10], q11 = p2[11], q12 = p2[12], q13 = p2[13], q14 = p2[14];
    float conf0 = q10.x, px0 = q10.y, py0 = q11.x, pw0 = q11.y, ph0 = q12.x;
    float conf1 = q12.y, px1 = q13.x, py1 = q13.y, pw1 = q14.x, ph1 = q14.y;

    float t_x1 = tx - tw * 0.5f, t_x2 = tx + tw * 0.5f;
    float t_y1 = ty - th * 0.5f, t_y2 = ty + th * 0.5f;
    float ta = fabsf((t_x2 - t_x1) * (t_y2 - t_y1));

    float b_x1 = px0 - pw0 * 0.5f, b_x2 = px0 + pw0 * 0.5f;
    float b_y1 = py0 - ph0 * 0.5f, b_y2 = py0 + ph0 * 0.5f;
    float ix = fmaxf(fminf(t_x2, b_x2) - fmaxf(t_x1, b_x1), 0.f);
    float iy = fmaxf(fminf(t_y2, b_y2) - fmaxf(t_y1, b_y1), 0.f);
    float inter0 = ix * iy;
    float a0 = fabsf((b_x2 - b_x1) * (b_y2 - b_y1));
    float iou0 = inter0 * __builtin_amdgcn_rcpf(ta + a0 - inter0 + 1e-6f);

    float c_x1 = px1 - pw1 * 0.5f, c_x2 = px1 + pw1 * 0.5f;
    float c_y1 = py1 - ph1 * 0.5f, c_y2 = py1 + ph1 * 0.5f;
    float jx = fmaxf(fminf(t_x2, c_x2) - fmaxf(t_x1, c_x1), 0.f);
    float jy = fmaxf(fminf(t_y2, c_y2) - fmaxf(t_y1, c_y1), 0.f);
    float inter1 = jx * jy;
    float a1 = fabsf((c_x2 - c_x1) * (c_y2 - c_y1));
    float iou1 = inter1 * __builtin_amdgcn_rcpf(ta + a1 - inter1 + 1e-6f);

    bool sel1 = iou1 > iou0;
    float conf = sel1 ? conf1 : conf0;
    float piou = sel1 ? iou1 : iou0;
    float px = sel1 ? px1 : px0;
    float py = sel1 ? py1 : py0;
    float pw = sel1 ? pw1 : pw0;
    float ph = sel1 ? ph1 : ph0;

    float dx = tx - px, dy = ty - py;
    float xy = dx * dx + dy * dy;
    float sgw = (pw > 0.f) ? 1.f : ((pw < 0.f) ? -1.f : 0.f);
    float sgh = (ph > 0.f) ? 1.f : ((ph < 0.f) ? -1.f : 0.f);
    float dw = __builtin_amdgcn_sqrtf(tw) - sgw * __builtin_amdgcn_sqrtf(fabsf(pw) + 1e-6f);
    float dh = __builtin_amdgcn_sqrtf(th) - sgh * __builtin_amdgcn_sqrtf(fabsf(ph) + 1e-6f);
    float wh = dw * dw + dh * dh;
    float dob = piou - conf;

    return obj * (5.f * (xy + wh) + dob * dob + cl) + (1.f - obj) * (0.5f * conf * conf);
}

// Single-wave block, barrierless double-buffered streaming:
//   stage(b0,T0); stage(b1,T1);
//   loop: vmcnt(16) [only next tile outstanding] -> compute buf[cur]
//         -> lgkmcnt(0) -> restage buf[cur] with tile t+2
// No __syncthreads, no vmcnt(0) drain in the steady state.
__global__ __launch_bounds__(WAVE) void yolo_main(
    const float* __restrict__ yt, const float* __restrict__ yp,
    float* __restrict__ partial, int ncells, int ntiles) {
    __shared__ float st[2][LDS_FLOATS];
    __shared__ float sp[2][LDS_FLOATS];

    const int lane = threadIdx.x;
    const long total_v4 = ((long)ncells * CH) / 4;   // divisible by 4 for this shape
    const float4* gt = (const float4*)yt;
    const float4* gp = (const float4*)yp;

    // contiguous, perfectly-balanced tile ranges (49 per block at bench shape)
    const int b = blockIdx.x;
    const int tpb = ntiles / gridDim.x;
    const int rem = ntiles - tpb * gridDim.x;
    const int n = tpb + (b < rem ? 1 : 0);
    const int start = b * tpb + (b < rem ? b : rem);

    float acc = 0.f;

    // 8 full wave-loads per array (512 chunks; 480 real + 32 pad clamped in-bounds —
    // pad re-reads next tile's head: L1/L2 hit, ~0 HBM cost; LDS pad never read).
#define STAGE(BUF, TILE) do {                                                  \
    long _base = (long)(TILE) * TILE_V4;                                       \
    _Pragma("unroll")                                                          \
    for (int _i = 0; _i < 8; ++_i) {                                           \
        long _idx = _base + _i * WAVE + lane;                                  \
        if (_idx >= total_v4) _idx = total_v4 - 1;                             \
        __builtin_amdgcn_global_load_lds(                                      \
            (const __attribute__((address_space(1))) void*)(gt + _idx),       \
            (__attribute__((address_space(3))) void*)(&st[BUF][_i * WAVE * 4]),\
            16, 0, 0);                                                         \
        __builtin_amdgcn_global_load_lds(                                      \
            (const __attribute__((address_space(1))) void*)(gp + _idx),       \
            (__attribute__((address_space(3))) void*)(&sp[BUF][_i * WAVE * 4]),\
            16, 0, 0);                                                         \
    }                                                                          \
} while (0)

    if (n > 0) STAGE(0, start);
    if (n > 1) STAGE(1, start + 1);

    for (int t = 0; t < n; ++t) {
        const int cur = t & 1;
        if (t + 1 < n) {
            // wait for tile t only; tile t+1's 16 loads stay in flight
            asm volatile("s_waitcnt vmcnt(16)" ::: "memory");
        } else {
            asm volatile("s_waitcnt vmcnt(0)" ::: "memory");
        }
        __builtin_amdgcn_sched_barrier(0);

        const int cell = (start + t) * CELLS_PER_TILE + lane;
        if (cell < ncells)
            acc += cell_loss(&st[cur][lane * CH], &sp[cur][lane * CH]);

        if (t + 2 < n) {
            // all ds_reads of buf[cur] must have executed before gll overwrites it
            asm volatile("s_waitcnt lgkmcnt(0)" ::: "memory");
            __builtin_amdgcn_sched_barrier(0);
            STAGE(cur, start + t + 2);
        }
    }
#undef STAGE

    // single-wave reduction, plain store (no atomics, no d_out memset needed)
#pragma unroll
    for (int off = 32; off > 0; off >>= 1)
        acc += __shfl_down(acc, off, 64);
    if (lane == 0) partial[b] = acc;
}

__global__ __launch_bounds__(1024) void reduce_partials(
    const float* __restrict__ partial, float* __restrict__ out, int n) {
    __shared__ float ws[16];
    const int tid = threadIdx.x;
    float v = (tid < n) ? partial[tid] : 0.f;
#pragma unroll
    for (int off = 32; off > 0; off >>= 1)
        v += __shfl_down(v, off, 64);
    if ((tid & 63) == 0) ws[tid >> 6] = v;
    __syncthreads();
    if (tid == 0) {
        float s = 0.f;
#pragma unroll
        for (int w = 0; w < 16; ++w) s += ws[w];
        out[0] = s;
    }
}

extern "C" void kernel_launch(void* const* d_in, const int* in_sizes, int n_in,
                              void* d_out, int out_size, void* d_ws, size_t ws_size,
                              hipStream_t stream) {
    const float* yt = (const float*)d_in[0];
    const float* yp = (const float*)d_in[1];
    float* partial = (float*)d_ws;
    float* out = (float*)d_out;

    const int ncells = in_sizes[0] / CH;                       // 3,211,264
    const int ntiles = (ncells + CELLS_PER_TILE - 1) / CELLS_PER_TILE;  // 50,176

    const int nb = NBLOCKS < ntiles ? NBLOCKS : ntiles;
    yolo_main<<<nb, WAVE, 0, stream>>>(yt, yp, partial, ncells, ntiles);
    reduce_partials<<<1, 1024, 0, stream>>>(partial, out, nb);
}